// Round 7
// baseline (220.765 us; speedup 1.0000x reference)
//
#include <hip/hip_runtime.h>

#define TM 256
#define TN 256
#define BK 128   // fp8 bytes per K-slab = one 16x16x128 MFMA k-step

typedef float f32x4 __attribute__((ext_vector_type(4)));
typedef int   i32x4 __attribute__((ext_vector_type(4)));
typedef int   i32x8 __attribute__((ext_vector_type(8)));

// E8M0 scales: value = 2^(byte-127). A-scale = 2^0; B holds cent*2^6, B-scale = 2^-6.
#define SCALE_A 127
#define SCALE_B 121

__device__ __forceinline__ unsigned char f2fp8(float f) {
    int p = __builtin_amdgcn_cvt_pk_fp8_f32(f, f, 0, false);
    return (unsigned char)(p & 0xff);
}

// ---- prep_both: fused prep_w (blocks [0,1024)) + prep_x (blocks [1024,9216)). ----
__global__ __launch_bounds__(256) void prep_both(const float* __restrict__ W,
                                                 unsigned char* __restrict__ c8,
                                                 float* __restrict__ s,
                                                 const float* __restrict__ x,
                                                 unsigned int* __restrict__ x8,
                                                 float* __restrict__ x2) {
    __shared__ float tile[64][65];
    __shared__ float cred[4][64];
    const int tid = threadIdx.x;

    if (blockIdx.x < 1024) {            // ---- prep_w body ----
        const int tx = tid & 63;
        const int ty = tid >> 6;
        const int q0 = (blockIdx.x & 15) * 64;
        const int e0 = (blockIdx.x >> 4) * 64;   // e = r*1024 + d
        const int r  = e0 >> 10;
        const int d0 = e0 & 1023;

        float csum = 0.f;
        #pragma unroll
        for (int p = 0; p < 16; p++) {
            const int er = p * 4 + ty;
            const float v = W[(size_t)(e0 + er) * 1024 + q0 + tx];
            tile[er][tx] = v;
            csum += v * v;
        }
        cred[ty][tx] = csum;
        __syncthreads();
        if (ty == 0) {
            atomicAdd(&s[4 * (q0 + tx) + r],
                      cred[0][tx] + cred[1][tx] + cred[2][tx] + cred[3][tx]);
        }
        #pragma unroll
        for (int p = 0; p < 16; p++) {
            const int q = q0 + p * 4 + ty;
            const float v = tile[tx][p * 4 + ty];
            c8[(size_t)(4 * q + r) * 1024 + d0 + tx] = f2fp8(v * 64.f);
        }
    } else {                            // ---- prep_x body ----
        const int b = blockIdx.x - 1024;
        const float4 v = ((const float4*)(x + (size_t)b * 1024))[tid];
        float sum = v.x * v.x + v.y * v.y + v.z * v.z + v.w * v.w;
        int p = __builtin_amdgcn_cvt_pk_fp8_f32(v.x, v.y, 0, false);
        p = __builtin_amdgcn_cvt_pk_fp8_f32(v.z, v.w, p, true);
        x8[(size_t)b * 256 + tid] = (unsigned int)p;
        #pragma unroll
        for (int o = 32; o > 0; o >>= 1) sum += __shfl_down(sum, o, 64);
        if ((tid & 63) == 0) cred[0][tid >> 6] = sum;
        __syncthreads();
        if (tid == 0) x2[b] = cred[0][0] + cred[0][1] + cred[0][2] + cred[0][3];
    }
}

// ---- gemm_bt: out[m][n] = 2*sum_k A[m][k]*Bt[n][k] - x2[m] - s[n] - bias[n] ----
// R11 vs R10 (gemm ~57 us; MFMA 15, writes 21, staging 15 -> gap was LDS BW):
// At 128²/4-wave each staged byte is ds_read by 2 waves -> ~1.15 MB LDS
// traffic per block, ~9 MB/CU ≈ 35-40 us of LDS-port time = the bottleneck
// (explains why occupancy didn't matter: LDS is shared per-CU).
// FIX: 256x256 tile, 8 waves (512 thr), 128 KB LDS dbuf (1 block/CU, still
// 2 waves/SIMD). Wave tile 128x64: LDS bytes/output 72 -> 32 (2.2x less),
// L2 staging traffic halved (256 MB), 32 MFMA per wave per slab (2x latency
// absorption), 4x fewer block boundaries. Keep: counted-vmcnt dbuf pipeline
// (8 loads/thread/slab -> vmcnt(8)), XOR chunk swizzle, swapped-operand MFMA,
// setprio, swizzled-LDS epilogue transpose (two 128-row passes, conflict-free).
__global__ __launch_bounds__(512, 2) void gemm_bt(const unsigned char* __restrict__ A,
                                                  const unsigned char* __restrict__ Bt,
                                                  const float* __restrict__ x2,
                                                  const float* __restrict__ s,
                                                  const float* __restrict__ bias,
                                                  float* __restrict__ out,
                                                  int M, int N, int K) {
    __shared__ unsigned char smem[2 * TM * BK + 2 * TN * BK];   // 128 KB
    unsigned char* la = smem;                    // 64 KB (double-buffered A)
    unsigned char* lb = smem + 2 * TM * BK;      // 64 KB (double-buffered B)
    float* ftile = (float*)smem;                 // epilogue reuse: 128x256 f32 = 128 KB

    const int tid  = threadIdx.x;
    const int wave = tid >> 6;      // 0..7
    const int lane = tid & 63;
    const int quad = lane >> 4;
    const int l16  = lane & 15;
    const int wm   = wave & 1;      // m half: 128 rows
    const int wn   = wave >> 1;     // n quarter: 64 cols

    // XCD m-stripe swizzle: 512 blocks = 8 xcd x (4 mt x 16 nt)
    const int flat = blockIdx.x;
    const int xcd  = flat & 7;
    const int idx  = flat >> 3;                 // 0..63
    const int mt   = (idx & 3) | (xcd << 2);    // 0..31; 4 m-stripes (1 MB A) per XCD
    const int nt   = idx >> 2;                  // 0..15
    const int tile_m = mt * TM;
    const int tile_n = nt * TN;

    // staging: lane -> row (base + lane/8), slot (lane&7); source chunk XOR-swizzled
    const int srow8 = lane >> 3;
    const int gcol  = ((lane & 7) ^ srow8) * 16;
    const unsigned char* gA = A  + (size_t)(tile_m + wave * 32 + srow8) * K + gcol;
    const unsigned char* gB = Bt + (size_t)(tile_n + wave * 32 + srow8) * K + gcol;

    f32x4 acc[8][4];
    #pragma unroll
    for (int i = 0; i < 8; i++)
        #pragma unroll
        for (int j = 0; j < 4; j++) acc[i][j] = (f32x4){0.f, 0.f, 0.f, 0.f};

    const int sw = l16 & 7;
    const int slot_lo = ((2 * quad) ^ sw) * 16;
    const int slot_hi = ((2 * quad + 1) ^ sw) * 16;

    // stage one K-slab (byte offset kt): each wave stages A rows [wave*32,+32)
    // and B rows [wave*32,+32) -> 8 global_load_lds per thread per slab
    auto stage = [&](int kt, int buf) {
        unsigned char* lab = la + buf * (TM * BK);
        unsigned char* lbb = lb + buf * (TN * BK);
        #pragma unroll
        for (int i = 0; i < 4; i++) {
            __builtin_amdgcn_global_load_lds(
                (const __attribute__((address_space(1))) void*)(gA + (size_t)(i * 8) * K + kt),
                (__attribute__((address_space(3))) void*)(lab + (wave * 32 + i * 8) * BK),
                16, 0, 0);
        }
        #pragma unroll
        for (int j = 0; j < 4; j++) {
            __builtin_amdgcn_global_load_lds(
                (const __attribute__((address_space(1))) void*)(gB + (size_t)(j * 8) * K + kt),
                (__attribute__((address_space(3))) void*)(lbb + (wave * 32 + j * 8) * BK),
                16, 0, 0);
        }
    };

    const int nkt = K / BK;   // 8
    stage(0, 0);
    int cur = 0;
    for (int t = 0; t < nkt; ++t) {
        if (t + 1 < nkt) {
            stage((t + 1) * BK, cur ^ 1);
            // 8 new loads outstanding; wait until only those remain -> slab t resident
            asm volatile("s_waitcnt vmcnt(8)" ::: "memory");
        } else {
            asm volatile("s_waitcnt vmcnt(0)" ::: "memory");
        }
        __builtin_amdgcn_s_barrier();   // all waves' slab-t loads now in LDS

        const unsigned char* pa_row = la + cur * (TM * BK) + (wm * 128 + l16) * BK;
        const unsigned char* pb_row = lb + cur * (TN * BK) + (wn * 64 + l16) * BK;

        i32x8 bf[4];
        #pragma unroll
        for (int j = 0; j < 4; j++) {
            i32x4 lo = *(const i32x4*)(pb_row + j * 16 * BK + slot_lo);
            i32x4 hi = *(const i32x4*)(pb_row + j * 16 * BK + slot_hi);
            bf[j] = __builtin_shufflevector(lo, hi, 0, 1, 2, 3, 4, 5, 6, 7);
        }
        __builtin_amdgcn_s_setprio(1);
        #pragma unroll
        for (int i = 0; i < 8; i++) {
            i32x4 lo = *(const i32x4*)(pa_row + i * 16 * BK + slot_lo);
            i32x4 hi = *(const i32x4*)(pa_row + i * 16 * BK + slot_hi);
            i32x8 af = __builtin_shufflevector(lo, hi, 0, 1, 2, 3, 4, 5, 6, 7);
            #pragma unroll
            for (int j = 0; j < 4; j++)
                // swapped operands: D fragment transposed (row=n, col=m); scales swap too
                acc[i][j] = __builtin_amdgcn_mfma_scale_f32_16x16x128_f8f6f4(
                    bf[j], af, acc[i][j], 0, 0, 0, SCALE_B, 0, SCALE_A);
        }
        __builtin_amdgcn_s_setprio(0);

        __builtin_amdgcn_s_barrier();   // buf `cur` free for reuse next iteration
        cur ^= 1;
    }

    // ---- epilogue: two 128-row passes through ftile (128x256 f32 = 128 KB) ----
    // fragment (transposed): m_local = wm*128 + i*16 + l16, n_local = wn*64 + j*16 + quad*4+rr
    float xm[8];
    #pragma unroll
    for (int i = 0; i < 8; i++)
        xm[i] = x2[tile_m + wm * 128 + i * 16 + l16];

    #pragma unroll
    for (int p = 0; p < 2; ++p) {
        if (wm == p) {
            #pragma unroll
            for (int j = 0; j < 4; j++) {
                const int n0 = tile_n + wn * 64 + j * 16 + quad * 4;
                const f32x4 sv = *(const f32x4*)(s + n0);
                const f32x4 bv = *(const f32x4*)(bias + n0);
                #pragma unroll
                for (int i = 0; i < 8; i++) {
                    f32x4 v;
                    #pragma unroll
                    for (int rr = 0; rr < 4; rr++)
                        v[rr] = 2.f * acc[i][j][rr] - xm[i] - sv[rr] - bv[rr];
                    const int ml = i * 16 + l16;            // row within pass (0..127)
                    const int cn = wn * 16 + j * 4 + quad;  // f32x4 chunk (0..63)
                    *(f32x4*)(ftile + ml * 256 + ((cn ^ ((ml & 7) << 2)) << 2)) = v;
                }
            }
        }
        __syncthreads();
        // read back row-major: each wave covers 1 row x 1 KB contiguous per instruction
        #pragma unroll
        for (int it = 0; it < 16; ++it) {
            const int r = it * 8 + wave;     // 0..127
            const int c = lane;              // f32x4 chunk within row (0..63)
            const f32x4 v = *(const f32x4*)(ftile + r * 256 + ((c ^ ((r & 7) << 2)) << 2));
            __builtin_nontemporal_store(v,
                (f32x4*)(out + (size_t)(tile_m + p * 128 + r) * N + tile_n + c * 4));
        }
        if (p == 0) __syncthreads();   // readback done before pass-1 overwrites ftile
    }
}

extern "C" void kernel_launch(void* const* d_in, const int* in_sizes, int n_in,
                              void* d_out, int out_size, void* d_ws, size_t ws_size,
                              hipStream_t stream) {
    const float* x    = (const float*)d_in[0];
    const float* w    = (const float*)d_in[1];
    const float* bias = (const float*)d_in[2];
    float* out = (float*)d_out;

    const int C = in_sizes[2];              // 4096
    const int D = in_sizes[1] / C;          // 1024
    const int B = in_sizes[0] / D;          // 8192

    unsigned char* x8 = (unsigned char*)d_ws;              // B*D fp8 = 8 MB
    unsigned char* c8 = x8 + (size_t)B * D;                // C*D fp8 = 4 MB
    float* x2 = (float*)(c8 + (size_t)C * D);              // B fp32
    float* s  = x2 + B;                                    // C fp32

    hipMemsetAsync(s, 0, (size_t)C * sizeof(float), stream);   // s = 0; bias folded into gemm epilogue
    prep_both<<<1024 + B, 256, 0, stream>>>(w, c8, s, x, (unsigned int*)x8, x2);
    const int nblocks = (B / TM) * (C / TN);                   // 512 = 2 rounds/CU
    gemm_bt<<<nblocks, 512, 0, stream>>>(x8, c8, x2, s, bias, out, B, C, D);
}

// Round 9
// 202.272 us; speedup vs baseline: 1.0914x; 1.0914x over previous
//
#include <hip/hip_runtime.h>

#define TM 128
#define TN 128
#define BK 128   // fp8 bytes per K-slab = one 16x16x128 MFMA k-step

typedef float f32x4 __attribute__((ext_vector_type(4)));
typedef int   i32x4 __attribute__((ext_vector_type(4)));
typedef int   i32x8 __attribute__((ext_vector_type(8)));

// E8M0 scales: value = 2^(byte-127). A-scale = 2^0; B holds cent*2^6, B-scale = 2^-6.
#define SCALE_A 127
#define SCALE_B 121

// ---- prep_both: fused prep_w (blocks [0,1024)) + prep_x (blocks [1024,9216)).
// R12: c8 write vectorized — each lane packs 4 consecutive d-values into one
// u32 (was 1 byte/lane = 64 B per wave-instr; now 256 B), 4 iters instead of 16.
__global__ __launch_bounds__(256) void prep_both(const float* __restrict__ W,
                                                 unsigned char* __restrict__ c8,
                                                 float* __restrict__ s,
                                                 const float* __restrict__ x,
                                                 unsigned int* __restrict__ x8,
                                                 float* __restrict__ x2) {
    __shared__ float tile[64][65];
    __shared__ float cred[4][64];
    const int tid = threadIdx.x;

    if (blockIdx.x < 1024) {            // ---- prep_w body ----
        const int tx = tid & 63;
        const int ty = tid >> 6;
        const int q0 = (blockIdx.x & 15) * 64;
        const int e0 = (blockIdx.x >> 4) * 64;   // e = r*1024 + d
        const int r  = e0 >> 10;
        const int d0 = e0 & 1023;

        float csum = 0.f;
        #pragma unroll
        for (int p = 0; p < 16; p++) {
            const int er = p * 4 + ty;
            const float v = W[(size_t)(e0 + er) * 1024 + q0 + tx];
            tile[er][tx] = v;
            csum += v * v;
        }
        cred[ty][tx] = csum;
        __syncthreads();
        if (ty == 0) {
            atomicAdd(&s[4 * (q0 + tx) + r],
                      cred[0][tx] + cred[1][tx] + cred[2][tx] + cred[3][tx]);
        }
        // write c8: per p, thread (qq = p*16 + tid>>4, dg = tid&15) packs
        // tile[dg*4+0..3][qq] -> u32 at row 4*(q0+qq)+r, col d0+dg*4
        #pragma unroll
        for (int p = 0; p < 4; p++) {
            const int qq = p * 16 + (tid >> 4);
            const int dg = tid & 15;
            const float v0 = tile[dg * 4 + 0][qq] * 64.f;
            const float v1 = tile[dg * 4 + 1][qq] * 64.f;
            const float v2 = tile[dg * 4 + 2][qq] * 64.f;
            const float v3 = tile[dg * 4 + 3][qq] * 64.f;
            int pk = __builtin_amdgcn_cvt_pk_fp8_f32(v0, v1, 0, false);
            pk = __builtin_amdgcn_cvt_pk_fp8_f32(v2, v3, pk, true);
            *(unsigned int*)(c8 + (size_t)(4 * (q0 + qq) + r) * 1024 + d0 + dg * 4) =
                (unsigned int)pk;
        }
    } else {                            // ---- prep_x body ----
        const int b = blockIdx.x - 1024;
        const float4 v = ((const float4*)(x + (size_t)b * 1024))[tid];
        float sum = v.x * v.x + v.y * v.y + v.z * v.z + v.w * v.w;
        int p = __builtin_amdgcn_cvt_pk_fp8_f32(v.x, v.y, 0, false);
        p = __builtin_amdgcn_cvt_pk_fp8_f32(v.z, v.w, p, true);
        x8[(size_t)b * 256 + tid] = (unsigned int)p;
        #pragma unroll
        for (int o = 32; o > 0; o >>= 1) sum += __shfl_down(sum, o, 64);
        if ((tid & 63) == 0) cred[0][tid >> 6] = sum;
        __syncthreads();
        if (tid == 0) x2[b] = cred[0][0] + cred[0][1] + cred[0][2] + cred[0][3];
    }
}

// ---- gemm_bt: out[m][n] = 2*sum_k A[m][k]*Bt[n][k] - x2[m] - s[n] - bias[n] ----
// R12 = R10 (best, gemm ~57) with ONE change: epilogue stores are NORMAL
// (not nontemporal). Theory: R10's ~57 us is ADDITIVE writes(21)+MFMA(15)+
// staging because the 2 co-resident blocks run in lockstep -> epilogue store
// bursts coincide, and NT streams them synchronously toward HBM. Normal
// stores complete at L2 speed, leaving dirty lines that drain to HBM
// asynchronously UNDER the next block's K-loop — overlap via cache, burst
// locality preserved. (R11's 256² tile REVERTED: 1 block/CU made the
// epilogue fully serial, gemm ~70. LDS-BW theory falsified.)
__global__ __launch_bounds__(256, 2) void gemm_bt(const unsigned char* __restrict__ A,
                                                  const unsigned char* __restrict__ Bt,
                                                  const float* __restrict__ x2,
                                                  const float* __restrict__ s,
                                                  const float* __restrict__ bias,
                                                  float* __restrict__ out,
                                                  int M, int N, int K) {
    __shared__ unsigned char smem[2 * TM * BK + 2 * TN * BK];   // 64 KB
    unsigned char* la = smem;                    // 32 KB (double-buffered A)
    unsigned char* lb = smem + 2 * TM * BK;      // 32 KB (double-buffered B)
    float* ftile = (float*)smem;                 // epilogue reuse: 128x128 f32 = 64 KB

    const int tid  = threadIdx.x;
    const int wave = tid >> 6;
    const int lane = tid & 63;
    const int quad = lane >> 4;
    const int l16  = lane & 15;
    const int wm   = wave & 1;     // m half: 64 rows
    const int wn   = wave >> 1;    // n half: 64 cols

    // XCD m-stripe swizzle (m-tiles = M/TM = 64, n-tiles = N/TN = 32)
    const int flat = blockIdx.x;    // 2048 blocks
    const int xcd  = flat & 7;
    const int idx  = flat >> 3;     // 0..255
    const int mt   = (idx & 7) | (xcd << 3);   // 8 m-tiles per XCD -> 1 MB A-stripe in its L2
    const int nt   = idx >> 3;      // 0..31
    const int tile_m = mt * TM;
    const int tile_n = nt * TN;

    // staging: lane -> row (base + lane/8), slot (lane&7); source chunk XOR-swizzled
    const int srow8 = lane >> 3;
    const int gcol  = ((lane & 7) ^ srow8) * 16;
    const unsigned char* gA = A  + (size_t)(tile_m + wave * 32 + srow8) * K + gcol;
    const unsigned char* gB = Bt + (size_t)(tile_n + wave * 32 + srow8) * K + gcol;

    f32x4 acc[4][4];
    #pragma unroll
    for (int i = 0; i < 4; i++)
        #pragma unroll
        for (int j = 0; j < 4; j++) acc[i][j] = (f32x4){0.f, 0.f, 0.f, 0.f};

    const int sw = l16 & 7;
    const int slot_lo = ((2 * quad) ^ sw) * 16;
    const int slot_hi = ((2 * quad + 1) ^ sw) * 16;

    // stage one K-slab (byte offset kt) into buffer `buf`: 4 A-rows-of-8 + 4 B-rows-of-8
    auto stage = [&](int kt, int buf) {
        unsigned char* lab = la + buf * (TM * BK);
        unsigned char* lbb = lb + buf * (TN * BK);
        #pragma unroll
        for (int i = 0; i < 4; i++) {
            __builtin_amdgcn_global_load_lds(
                (const __attribute__((address_space(1))) void*)(gA + (size_t)(i * 8) * K + kt),
                (__attribute__((address_space(3))) void*)(lab + (wave * 32 + i * 8) * BK),
                16, 0, 0);
        }
        #pragma unroll
        for (int j = 0; j < 4; j++) {
            __builtin_amdgcn_global_load_lds(
                (const __attribute__((address_space(1))) void*)(gB + (size_t)(j * 8) * K + kt),
                (__attribute__((address_space(3))) void*)(lbb + (wave * 32 + j * 8) * BK),
                16, 0, 0);
        }
    };

    const int nkt = K / BK;   // 8
    stage(0, 0);
    int cur = 0;
    for (int t = 0; t < nkt; ++t) {
        if (t + 1 < nkt) {
            stage((t + 1) * BK, cur ^ 1);
            // 8 new loads outstanding; wait until only those remain -> slab t resident
            asm volatile("s_waitcnt vmcnt(8)" ::: "memory");
        } else {
            asm volatile("s_waitcnt vmcnt(0)" ::: "memory");
        }
        __builtin_amdgcn_s_barrier();   // all waves' slab-t loads now in LDS

        const unsigned char* pa_row = la + cur * (TM * BK) + (wm * 64 + l16) * BK;
        const unsigned char* pb_row = lb + cur * (TN * BK) + (wn * 64 + l16) * BK;

        i32x8 af[4];
        #pragma unroll
        for (int i = 0; i < 4; i++) {
            i32x4 lo = *(const i32x4*)(pa_row + i * 16 * BK + slot_lo);
            i32x4 hi = *(const i32x4*)(pa_row + i * 16 * BK + slot_hi);
            af[i] = __builtin_shufflevector(lo, hi, 0, 1, 2, 3, 4, 5, 6, 7);
        }
        i32x8 bf[4];
        #pragma unroll
        for (int j = 0; j < 4; j++) {
            i32x4 lo = *(const i32x4*)(pb_row + j * 16 * BK + slot_lo);
            i32x4 hi = *(const i32x4*)(pb_row + j * 16 * BK + slot_hi);
            bf[j] = __builtin_shufflevector(lo, hi, 0, 1, 2, 3, 4, 5, 6, 7);
        }
        __builtin_amdgcn_s_setprio(1);
        #pragma unroll
        for (int j = 0; j < 4; j++)
            #pragma unroll
            for (int i = 0; i < 4; i++)
                // swapped operands: D fragment transposed (row=n, col=m); scales swap too
                acc[i][j] = __builtin_amdgcn_mfma_scale_f32_16x16x128_f8f6f4(
                    bf[j], af[i], acc[i][j], 0, 0, 0, SCALE_B, 0, SCALE_A);
        __builtin_amdgcn_s_setprio(0);

        __builtin_amdgcn_s_barrier();   // buf `cur` free for reuse next iteration
        cur ^= 1;
    }

    // ---- epilogue: finish math in regs, swizzled LDS transpose, coalesced stores ----
    // fragment (transposed): m_local = wm*64 + i*16 + l16, n_local = wn*64 + j*16 + quad*4+rr
    // ftile flat [128][128] f32; chunk index cn = n_local>>2; swizzle cn ^= (m_local&7)<<2.
    float xm[4];
    #pragma unroll
    for (int i = 0; i < 4; i++)
        xm[i] = x2[tile_m + wm * 64 + i * 16 + l16];
    #pragma unroll
    for (int j = 0; j < 4; j++) {
        const int n0 = tile_n + wn * 64 + j * 16 + quad * 4;
        const f32x4 sv = *(const f32x4*)(s + n0);
        const f32x4 bv = *(const f32x4*)(bias + n0);
        #pragma unroll
        for (int i = 0; i < 4; i++) {
            f32x4 v;
            #pragma unroll
            for (int rr = 0; rr < 4; rr++)
                v[rr] = 2.f * acc[i][j][rr] - xm[i] - sv[rr] - bv[rr];
            const int ml = wm * 64 + i * 16 + l16;
            const int cn = wn * 16 + j * 4 + quad;
            *(f32x4*)(ftile + ml * 128 + ((cn ^ ((ml & 7) << 2)) << 2)) = v;
        }
    }
    __syncthreads();
    // read back row-major: wave covers 2 rows x 512 B contiguous per instruction.
    // NORMAL stores (no NT): land in L2, drain to HBM async under next block's K-loop.
    #pragma unroll
    for (int it = 0; it < 16; ++it) {
        const int r = it * 8 + (tid >> 5);   // 0..127
        const int c = tid & 31;              // f32x4 chunk within row
        const f32x4 v = *(const f32x4*)(ftile + r * 128 + ((c ^ ((r & 7) << 2)) << 2));
        *(f32x4*)(out + (size_t)(tile_m + r) * N + tile_n + c * 4) = v;
    }
}

extern "C" void kernel_launch(void* const* d_in, const int* in_sizes, int n_in,
                              void* d_out, int out_size, void* d_ws, size_t ws_size,
                              hipStream_t stream) {
    const float* x    = (const float*)d_in[0];
    const float* w    = (const float*)d_in[1];
    const float* bias = (const float*)d_in[2];
    float* out = (float*)d_out;

    const int C = in_sizes[2];              // 4096
    const int D = in_sizes[1] / C;          // 1024
    const int B = in_sizes[0] / D;          // 8192

    unsigned char* x8 = (unsigned char*)d_ws;              // B*D fp8 = 8 MB
    unsigned char* c8 = x8 + (size_t)B * D;                // C*D fp8 = 4 MB
    float* x2 = (float*)(c8 + (size_t)C * D);              // B fp32
    float* s  = x2 + B;                                    // C fp32

    hipMemsetAsync(s, 0, (size_t)C * sizeof(float), stream);   // s = 0; bias folded into gemm epilogue
    prep_both<<<1024 + B, 256, 0, stream>>>(w, c8, s, x, (unsigned int*)x8, x2);
    const int nblocks = (B / TM) * (C / TN);
    gemm_bt<<<nblocks, 256, 0, stream>>>(x8, c8, x2, s, bias, out, B, C, D);
}